// Round 1
// baseline (1266.389 us; speedup 1.0000x reference)
//
#include <hip/hip_runtime.h>

// ---------------------------------------------------------------------------
// 3-layer GCN (DGL GraphConv, norm='both') on N=100k nodes, E=800k edges.
// All f32. Per layer: y=(h*inv_out)@W ; agg[dst]+=y[src]*w ; relu(agg*inv_in+b)
// ---------------------------------------------------------------------------

__global__ void deg_kernel(const int* __restrict__ src, const int* __restrict__ dst,
                           int* __restrict__ dego, int* __restrict__ degi, int E) {
    int e = blockIdx.x * blockDim.x + threadIdx.x;
    if (e < E) {
        atomicAdd(&dego[src[e]], 1);
        atomicAdd(&degi[dst[e]], 1);
    }
}

__global__ void invsqrt_kernel(const int* __restrict__ dego, const int* __restrict__ degi,
                               float* __restrict__ invo, float* __restrict__ invi, int N) {
    int i = blockIdx.x * blockDim.x + threadIdx.x;
    if (i < N) {
        int a = dego[i]; if (a < 1) a = 1;
        int b = degi[i]; if (b < 1) b = 1;
        invo[i] = 1.0f / sqrtf((float)a);
        invi[i] = 1.0f / sqrtf((float)b);
    }
}

// y[N][PC] = (h[N][128] * invo[row]) @ W[128][dact]   (cols j>=dact get 0)
// PC in {128, 64}. Thread tile: 4 rows x 4 cols. Block: 256 threads.
template<int PC>
__global__ __launch_bounds__(256)
void gemm_kernel(const float* __restrict__ h, const float* __restrict__ invo,
                 const float* __restrict__ W, int dact,
                 float* __restrict__ y, int N) {
    constexpr int NC   = PC / 4;     // col groups per row of the tile
    constexpr int NR   = 256 / NC;   // row groups
    constexpr int ROWS = NR * 4;     // rows per block
    __shared__ float Ws[128 * PC];
    __shared__ float hs[ROWS * 128];

    // Stage W (zero-pad cols >= dact)
    for (int idx = threadIdx.x; idx < 128 * PC; idx += 256) {
        int k = idx / PC, j = idx % PC;
        Ws[idx] = (j < dact) ? W[k * dact + j] : 0.0f;
    }

    const int row0 = blockIdx.x * ROWS;
    // Stage h tile, scaled by invo[row]
    for (int i = threadIdx.x; i < ROWS * 32; i += 256) {
        int r = i >> 5, c4 = i & 31;
        int row = row0 + r;
        float4 v = make_float4(0.f, 0.f, 0.f, 0.f);
        float s = 0.f;
        if (row < N) {
            v = *(const float4*)&h[(size_t)row * 128 + c4 * 4];
            s = invo[row];
        }
        v.x *= s; v.y *= s; v.z *= s; v.w *= s;
        *(float4*)&hs[r * 128 + c4 * 4] = v;
    }
    __syncthreads();

    const int tc = threadIdx.x % NC;
    const int tr = threadIdx.x / NC;
    const int jb = tc * 4;
    const int rb = tr * 4;

    float acc[4][4];
    #pragma unroll
    for (int r = 0; r < 4; ++r)
        #pragma unroll
        for (int c = 0; c < 4; ++c) acc[r][c] = 0.f;

    #pragma unroll 2
    for (int k = 0; k < 128; k += 4) {
        float4 wv0 = *(const float4*)&Ws[(k + 0) * PC + jb];
        float4 wv1 = *(const float4*)&Ws[(k + 1) * PC + jb];
        float4 wv2 = *(const float4*)&Ws[(k + 2) * PC + jb];
        float4 wv3 = *(const float4*)&Ws[(k + 3) * PC + jb];
        #pragma unroll
        for (int r = 0; r < 4; ++r) {
            float4 hv = *(const float4*)&hs[(rb + r) * 128 + k];
            acc[r][0] = fmaf(hv.x, wv0.x, acc[r][0]);
            acc[r][0] = fmaf(hv.y, wv1.x, acc[r][0]);
            acc[r][0] = fmaf(hv.z, wv2.x, acc[r][0]);
            acc[r][0] = fmaf(hv.w, wv3.x, acc[r][0]);
            acc[r][1] = fmaf(hv.x, wv0.y, acc[r][1]);
            acc[r][1] = fmaf(hv.y, wv1.y, acc[r][1]);
            acc[r][1] = fmaf(hv.z, wv2.y, acc[r][1]);
            acc[r][1] = fmaf(hv.w, wv3.y, acc[r][1]);
            acc[r][2] = fmaf(hv.x, wv0.z, acc[r][2]);
            acc[r][2] = fmaf(hv.y, wv1.z, acc[r][2]);
            acc[r][2] = fmaf(hv.z, wv2.z, acc[r][2]);
            acc[r][2] = fmaf(hv.w, wv3.z, acc[r][2]);
            acc[r][3] = fmaf(hv.x, wv0.w, acc[r][3]);
            acc[r][3] = fmaf(hv.y, wv1.w, acc[r][3]);
            acc[r][3] = fmaf(hv.z, wv2.w, acc[r][3]);
            acc[r][3] = fmaf(hv.w, wv3.w, acc[r][3]);
        }
    }

    #pragma unroll
    for (int r = 0; r < 4; ++r) {
        int row = row0 + rb + r;
        if (row < N) {
            *(float4*)&y[(size_t)row * PC + jb] =
                make_float4(acc[r][0], acc[r][1], acc[r][2], acc[r][3]);
        }
    }
}

// agg[dst[e]][f] += y[src[e]][f] * w[e], one thread per (edge, feature)
template<int D>
__global__ __launch_bounds__(256)
void scatter_kernel(const float* __restrict__ y, const int* __restrict__ src,
                    const int* __restrict__ dst, const float* __restrict__ w,
                    float* __restrict__ agg, int E) {
    int gid = blockIdx.x * blockDim.x + threadIdx.x;
    int e = gid / D;            // D is a power of two -> shift
    int f = gid & (D - 1);
    if (e < E) {
        float v = y[(size_t)src[e] * D + f] * w[e];
        atomicAdd(&agg[(size_t)dst[e] * D + f], v);
    }
}

// in-place: agg = relu(agg * invi[row] + b[col]), D = 128, float4
__global__ void finalize_relu(float* __restrict__ agg, const float* __restrict__ invi,
                              const float* __restrict__ b, int N) {
    int gid = blockIdx.x * blockDim.x + threadIdx.x;   // over N*32 float4s
    if (gid < N * 32) {
        int row = gid >> 5, c4 = gid & 31;
        float s = invi[row];
        float4 v = *(float4*)&agg[(size_t)gid * 4];
        float4 bb = *(const float4*)&b[c4 * 4];
        v.x = fmaxf(fmaf(v.x, s, bb.x), 0.f);
        v.y = fmaxf(fmaf(v.y, s, bb.y), 0.f);
        v.z = fmaxf(fmaf(v.z, s, bb.z), 0.f);
        v.w = fmaxf(fmaf(v.w, s, bb.w), 0.f);
        *(float4*)&agg[(size_t)gid * 4] = v;
    }
}

// out[row][c] = agg[row][c] * invi[row] + b[c]   (agg pitch 64, out pitch 47)
__global__ void finalize_out(const float* __restrict__ agg, const float* __restrict__ invi,
                             const float* __restrict__ b, float* __restrict__ out, int N) {
    int gid = blockIdx.x * blockDim.x + threadIdx.x;   // over N*47
    if (gid < N * 47) {
        int row = gid / 47;
        int c = gid - row * 47;
        out[gid] = fmaf(agg[(size_t)row * 64 + c], invi[row], b[c]);
    }
}

extern "C" void kernel_launch(void* const* d_in, const int* in_sizes, int n_in,
                              void* d_out, int out_size, void* d_ws, size_t ws_size,
                              hipStream_t stream) {
    const float* x  = (const float*)d_in[0];
    const int*   src = (const int*)d_in[1];
    const int*   dst = (const int*)d_in[2];
    const float* w  = (const float*)d_in[3];
    const float* W0 = (const float*)d_in[4];
    const float* b0 = (const float*)d_in[5];
    const float* W1 = (const float*)d_in[6];
    const float* b1 = (const float*)d_in[7];
    const float* W2 = (const float*)d_in[8];
    const float* b2 = (const float*)d_in[9];

    const int N = in_sizes[0] / 128;
    const int E = in_sizes[1];

    const size_t NB = (size_t)N * 128 * sizeof(float);
    char* p = (char*)d_ws;
    float* y    = (float*)p;  p += NB;                 // GEMM output (pitch 128 / 64)
    float* hb   = (float*)p;  p += NB;                 // h / agg ping buffer
    int*   dego = (int*)p;    p += (size_t)N * sizeof(int);
    int*   degi = (int*)p;    p += (size_t)N * sizeof(int);
    float* invo = (float*)p;  p += (size_t)N * sizeof(float);
    float* invi = (float*)p;  p += (size_t)N * sizeof(float);

    // degrees + norms
    hipMemsetAsync(dego, 0, 2 * (size_t)N * sizeof(int), stream);
    deg_kernel<<<(E + 255) / 256, 256, 0, stream>>>(src, dst, dego, degi, E);
    invsqrt_kernel<<<(N + 255) / 256, 256, 0, stream>>>(dego, degi, invo, invi, N);

    const int scat128_blocks = (int)(((size_t)E * 128 + 255) / 256);
    const int scat64_blocks  = (int)(((size_t)E * 64 + 255) / 256);

    // ---- layer 0: x -> hb ----
    gemm_kernel<128><<<(N + 31) / 32, 256, 0, stream>>>(x, invo, W0, 128, y, N);
    hipMemsetAsync(hb, 0, NB, stream);
    scatter_kernel<128><<<scat128_blocks, 256, 0, stream>>>(y, src, dst, w, hb, E);
    finalize_relu<<<(N * 32 + 255) / 256, 256, 0, stream>>>(hb, invi, b0, N);

    // ---- layer 1: hb -> hb ----
    gemm_kernel<128><<<(N + 31) / 32, 256, 0, stream>>>(hb, invo, W1, 128, y, N);
    hipMemsetAsync(hb, 0, NB, stream);
    scatter_kernel<128><<<scat128_blocks, 256, 0, stream>>>(y, src, dst, w + E, hb, E);
    finalize_relu<<<(N * 32 + 255) / 256, 256, 0, stream>>>(hb, invi, b1, N);

    // ---- layer 2: hb -> d_out (47 cols, padded to 64 internally) ----
    gemm_kernel<64><<<(N + 63) / 64, 256, 0, stream>>>(hb, invo, W2, 47, y, N);
    hipMemsetAsync(hb, 0, (size_t)N * 64 * sizeof(float), stream);
    scatter_kernel<64><<<scat64_blocks, 256, 0, stream>>>(y, src, dst, w + 2 * (size_t)E, hb, E);
    finalize_out<<<(N * 47 + 255) / 256, 256, 0, stream>>>(hb, invi, b2, (float*)d_out, N);
}

// Round 2
// 821.974 us; speedup vs baseline: 1.5407x; 1.5407x over previous
//
#include <hip/hip_runtime.h>

// ---------------------------------------------------------------------------
// 3-layer GCN (DGL GraphConv, norm='both') on N=100k nodes, E=800k edges.
// Round 2: pull-mode aggregation via dst-CSR (no float atomics), fused
// finalize (invi * agg + bias [+relu]) into the gather epilogue.
// Per layer: y = (h*invo) @ W ; h' = relu(CSR-gather(y)*invi + b)
// ---------------------------------------------------------------------------

__global__ void deg_kernel(const int* __restrict__ src, const int* __restrict__ dst,
                           int* __restrict__ dego, int* __restrict__ degi, int E) {
    int e = blockIdx.x * blockDim.x + threadIdx.x;
    if (e < E) {
        atomicAdd(&dego[src[e]], 1);
        atomicAdd(&degi[dst[e]], 1);
    }
}

__global__ void invsqrt_kernel(const int* __restrict__ dego, const int* __restrict__ degi,
                               float* __restrict__ invo, float* __restrict__ invi, int N) {
    int i = blockIdx.x * blockDim.x + threadIdx.x;
    if (i < N) {
        int a = dego[i]; if (a < 1) a = 1;
        int b = degi[i]; if (b < 1) b = 1;
        invo[i] = 1.0f / sqrtf((float)a);
        invi[i] = 1.0f / sqrtf((float)b);
    }
}

// ---- prefix sum of degi -> row_ofs (exclusive), 1024 elems per block ----
__global__ __launch_bounds__(256)
void scan_block(const int* __restrict__ deg, int* __restrict__ ofs,
                int* __restrict__ bsum, int N) {
    __shared__ int sh[256];
    const int base = blockIdx.x * 1024;
    const int t = threadIdx.x;
    int v[4]; int s = 0;
    #pragma unroll
    for (int i = 0; i < 4; ++i) {
        int idx = base + t * 4 + i;
        v[i] = (idx < N) ? deg[idx] : 0;
        s += v[i];
    }
    sh[t] = s;
    __syncthreads();
    #pragma unroll
    for (int off = 1; off < 256; off <<= 1) {
        int x = (t >= off) ? sh[t - off] : 0;
        __syncthreads();
        sh[t] += x;
        __syncthreads();
    }
    int excl = (t == 0) ? 0 : sh[t - 1];
    #pragma unroll
    for (int i = 0; i < 4; ++i) {
        int idx = base + t * 4 + i;
        if (idx < N) ofs[idx] = excl;
        excl += v[i];
    }
    if (t == 255) bsum[blockIdx.x] = sh[255];
}

__global__ __launch_bounds__(256)
void scan_top(int* __restrict__ bsum, int nb) {
    __shared__ int sh[256];
    const int t = threadIdx.x;
    sh[t] = (t < nb) ? bsum[t] : 0;
    __syncthreads();
    #pragma unroll
    for (int off = 1; off < 256; off <<= 1) {
        int x = (t >= off) ? sh[t - off] : 0;
        __syncthreads();
        sh[t] += x;
        __syncthreads();
    }
    int excl = (t == 0) ? 0 : sh[t - 1];
    if (t < nb) bsum[t] = excl;
}

// ofs[i] += bsum[i>>10]; cursor[i] = ofs[i]; ofs[N] = E
__global__ void add_offsets(int* __restrict__ ofs, const int* __restrict__ bsum,
                            int* __restrict__ cursor, int N, int E) {
    int i = blockIdx.x * blockDim.x + threadIdx.x;
    if (i < N) {
        int v = ofs[i] + bsum[i >> 10];
        ofs[i] = v;
        cursor[i] = v;
    }
    if (i == 0) ofs[N] = E;
}

__global__ void fill_csr(const int* __restrict__ src, const int* __restrict__ dst,
                         int* __restrict__ cursor, int* __restrict__ csr_src,
                         int* __restrict__ csr_eid, int E) {
    int e = blockIdx.x * blockDim.x + threadIdx.x;
    if (e < E) {
        int pos = atomicAdd(&cursor[dst[e]], 1);
        csr_src[pos] = src[e];
        csr_eid[pos] = e;
    }
}

// y[N][PC] = (h[N][128] * invo[row]) @ W[128][dact]   (cols j>=dact get 0)
template<int PC>
__global__ __launch_bounds__(256)
void gemm_kernel(const float* __restrict__ h, const float* __restrict__ invo,
                 const float* __restrict__ W, int dact,
                 float* __restrict__ y, int N) {
    constexpr int NC   = PC / 4;
    constexpr int NR   = 256 / NC;
    constexpr int ROWS = NR * 4;
    __shared__ float Ws[128 * PC];
    __shared__ float hs[ROWS * 128];

    for (int idx = threadIdx.x; idx < 128 * PC; idx += 256) {
        int k = idx / PC, j = idx % PC;
        Ws[idx] = (j < dact) ? W[k * dact + j] : 0.0f;
    }

    const int row0 = blockIdx.x * ROWS;
    for (int i = threadIdx.x; i < ROWS * 32; i += 256) {
        int r = i >> 5, c4 = i & 31;
        int row = row0 + r;
        float4 v = make_float4(0.f, 0.f, 0.f, 0.f);
        float s = 0.f;
        if (row < N) {
            v = *(const float4*)&h[(size_t)row * 128 + c4 * 4];
            s = invo[row];
        }
        v.x *= s; v.y *= s; v.z *= s; v.w *= s;
        *(float4*)&hs[r * 128 + c4 * 4] = v;
    }
    __syncthreads();

    const int tc = threadIdx.x % NC;
    const int tr = threadIdx.x / NC;
    const int jb = tc * 4;
    const int rb = tr * 4;

    float acc[4][4];
    #pragma unroll
    for (int r = 0; r < 4; ++r)
        #pragma unroll
        for (int c = 0; c < 4; ++c) acc[r][c] = 0.f;

    #pragma unroll 2
    for (int k = 0; k < 128; k += 4) {
        float4 wv0 = *(const float4*)&Ws[(k + 0) * PC + jb];
        float4 wv1 = *(const float4*)&Ws[(k + 1) * PC + jb];
        float4 wv2 = *(const float4*)&Ws[(k + 2) * PC + jb];
        float4 wv3 = *(const float4*)&Ws[(k + 3) * PC + jb];
        #pragma unroll
        for (int r = 0; r < 4; ++r) {
            float4 hv = *(const float4*)&hs[(rb + r) * 128 + k];
            acc[r][0] = fmaf(hv.x, wv0.x, acc[r][0]);
            acc[r][0] = fmaf(hv.y, wv1.x, acc[r][0]);
            acc[r][0] = fmaf(hv.z, wv2.x, acc[r][0]);
            acc[r][0] = fmaf(hv.w, wv3.x, acc[r][0]);
            acc[r][1] = fmaf(hv.x, wv0.y, acc[r][1]);
            acc[r][1] = fmaf(hv.y, wv1.y, acc[r][1]);
            acc[r][1] = fmaf(hv.z, wv2.y, acc[r][1]);
            acc[r][1] = fmaf(hv.w, wv3.y, acc[r][1]);
            acc[r][2] = fmaf(hv.x, wv0.z, acc[r][2]);
            acc[r][2] = fmaf(hv.y, wv1.z, acc[r][2]);
            acc[r][2] = fmaf(hv.z, wv2.z, acc[r][2]);
            acc[r][2] = fmaf(hv.w, wv3.z, acc[r][2]);
            acc[r][3] = fmaf(hv.x, wv0.w, acc[r][3]);
            acc[r][3] = fmaf(hv.y, wv1.w, acc[r][3]);
            acc[r][3] = fmaf(hv.z, wv2.w, acc[r][3]);
            acc[r][3] = fmaf(hv.w, wv3.w, acc[r][3]);
        }
    }

    #pragma unroll
    for (int r = 0; r < 4; ++r) {
        int row = row0 + rb + r;
        if (row < N) {
            *(float4*)&y[(size_t)row * PC + jb] =
                make_float4(acc[r][0], acc[r][1], acc[r][2], acc[r][3]);
        }
    }
}

// Pull-mode aggregation + fused finalize.
// D threads per node (D = feature pitch of y). out gets relu(acc*invi+b) when
// RELU, else acc*invi+b. FINAL: write pitch 47, only f<47.
template<int D, bool RELU, bool FINAL>
__global__ __launch_bounds__(256)
void gather_kernel(const float* __restrict__ y, const int* __restrict__ row_ofs,
                   const int* __restrict__ csr_src, const int* __restrict__ csr_eid,
                   const float* __restrict__ wl, const float* __restrict__ invi,
                   const float* __restrict__ b, float* __restrict__ out, int N) {
    constexpr int NPB = 256 / D;
    const int n = blockIdx.x * NPB + threadIdx.x / D;
    const int f = threadIdx.x & (D - 1);
    if (n >= N) return;
    const int p0 = row_ofs[n];
    const int p1 = row_ofs[n + 1];
    float acc = 0.f;
    for (int p = p0; p < p1; ++p) {
        int s = csr_src[p];           // wave-uniform
        float wv = wl[csr_eid[p]];    // wave-uniform
        acc = fmaf(y[(size_t)s * D + f], wv, acc);
    }
    float v = fmaf(acc, invi[n], (FINAL && f >= 47) ? 0.f : b[f]);
    if (RELU) v = fmaxf(v, 0.f);
    if (FINAL) {
        if (f < 47) out[(size_t)n * 47 + f] = v;
    } else {
        out[(size_t)n * D + f] = v;
    }
}

extern "C" void kernel_launch(void* const* d_in, const int* in_sizes, int n_in,
                              void* d_out, int out_size, void* d_ws, size_t ws_size,
                              hipStream_t stream) {
    const float* x  = (const float*)d_in[0];
    const int*   src = (const int*)d_in[1];
    const int*   dst = (const int*)d_in[2];
    const float* w  = (const float*)d_in[3];
    const float* W0 = (const float*)d_in[4];
    const float* b0 = (const float*)d_in[5];
    const float* W1 = (const float*)d_in[6];
    const float* b1 = (const float*)d_in[7];
    const float* W2 = (const float*)d_in[8];
    const float* b2 = (const float*)d_in[9];

    const int N = in_sizes[0] / 128;
    const int E = in_sizes[1];

    const size_t NB = (size_t)N * 128 * sizeof(float);
    char* p = (char*)d_ws;
    float* y       = (float*)p; p += NB;                        // GEMM out
    float* hb      = (float*)p; p += NB;                        // hidden ping
    int*   row_ofs = (int*)p;   p += (size_t)(N + 1) * sizeof(int);
    int*   cursor  = (int*)p;   p += (size_t)N * sizeof(int);
    int*   dego    = (int*)p;   p += (size_t)N * sizeof(int);
    int*   degi    = (int*)p;   p += (size_t)N * sizeof(int);
    float* invo    = (float*)p; p += (size_t)N * sizeof(float);
    float* invi    = (float*)p; p += (size_t)N * sizeof(float);
    int*   bsum    = (int*)p;   p += 256 * sizeof(int);
    int*   csr_src = (int*)p;   p += (size_t)E * sizeof(int);
    int*   csr_eid = (int*)p;   p += (size_t)E * sizeof(int);

    // ---- degrees, norms, CSR build (reused by all 3 layers) ----
    hipMemsetAsync(dego, 0, 2 * (size_t)N * sizeof(int), stream);
    deg_kernel<<<(E + 255) / 256, 256, 0, stream>>>(src, dst, dego, degi, E);
    invsqrt_kernel<<<(N + 255) / 256, 256, 0, stream>>>(dego, degi, invo, invi, N);

    const int nb = (N + 1023) / 1024;
    scan_block<<<nb, 256, 0, stream>>>(degi, row_ofs, bsum, N);
    scan_top<<<1, 256, 0, stream>>>(bsum, nb);
    add_offsets<<<(N + 255) / 256, 256, 0, stream>>>(row_ofs, bsum, cursor, N, E);
    fill_csr<<<(E + 255) / 256, 256, 0, stream>>>(src, dst, cursor, csr_src, csr_eid, E);

    // ---- layer 0: x -> hb ----
    gemm_kernel<128><<<(N + 31) / 32, 256, 0, stream>>>(x, invo, W0, 128, y, N);
    gather_kernel<128, true, false><<<(N + 1) / 2, 256, 0, stream>>>(
        y, row_ofs, csr_src, csr_eid, w, invi, b0, hb, N);

    // ---- layer 1: hb -> hb ----
    gemm_kernel<128><<<(N + 31) / 32, 256, 0, stream>>>(hb, invo, W1, 128, y, N);
    gather_kernel<128, true, false><<<(N + 1) / 2, 256, 0, stream>>>(
        y, row_ofs, csr_src, csr_eid, w + E, invi, b1, hb, N);

    // ---- layer 2: hb -> d_out (47 cols, y padded to 64) ----
    gemm_kernel<64><<<(N + 63) / 64, 256, 0, stream>>>(hb, invo, W2, 47, y, N);
    gather_kernel<64, false, true><<<(N + 3) / 4, 256, 0, stream>>>(
        y, row_ofs, csr_src, csr_eid, w + 2 * (size_t)E, invi, b2, (float*)d_out, N);
}

// Round 3
// 514.521 us; speedup vs baseline: 2.4613x; 1.5976x over previous
//
#include <hip/hip_runtime.h>

// ---------------------------------------------------------------------------
// 3-layer GCN (DGL GraphConv, norm='both') on N=100k nodes, E=800k edges.
// Round 3: y stored bf16 (halves gather bytes), CSR metadata packed as
// (src, w) float2 per layer (one broadcast load per edge), edge loop
// unrolled x2 with independent loads.
// Per layer: y = bf16((h*invo) @ W) ; h' = relu(CSR-gather(y)*invi + b)
// ---------------------------------------------------------------------------

__device__ __forceinline__ unsigned short f2bf(float f) {
    unsigned int u = __float_as_uint(f);
    u += 0x7FFFu + ((u >> 16) & 1u);   // round-to-nearest-even
    return (unsigned short)(u >> 16);
}
__device__ __forceinline__ float bf2f(unsigned short v) {
    return __uint_as_float((unsigned int)v << 16);
}

__global__ void deg_kernel(const int* __restrict__ src, const int* __restrict__ dst,
                           int* __restrict__ dego, int* __restrict__ degi, int E) {
    int e = blockIdx.x * blockDim.x + threadIdx.x;
    if (e < E) {
        atomicAdd(&dego[src[e]], 1);
        atomicAdd(&degi[dst[e]], 1);
    }
}

__global__ void invsqrt_kernel(const int* __restrict__ dego, const int* __restrict__ degi,
                               float* __restrict__ invo, float* __restrict__ invi, int N) {
    int i = blockIdx.x * blockDim.x + threadIdx.x;
    if (i < N) {
        int a = dego[i]; if (a < 1) a = 1;
        int b = degi[i]; if (b < 1) b = 1;
        invo[i] = 1.0f / sqrtf((float)a);
        invi[i] = 1.0f / sqrtf((float)b);
    }
}

// ---- prefix sum of degi -> row_ofs (exclusive), 1024 elems per block ----
__global__ __launch_bounds__(256)
void scan_block(const int* __restrict__ deg, int* __restrict__ ofs,
                int* __restrict__ bsum, int N) {
    __shared__ int sh[256];
    const int base = blockIdx.x * 1024;
    const int t = threadIdx.x;
    int v[4]; int s = 0;
    #pragma unroll
    for (int i = 0; i < 4; ++i) {
        int idx = base + t * 4 + i;
        v[i] = (idx < N) ? deg[idx] : 0;
        s += v[i];
    }
    sh[t] = s;
    __syncthreads();
    #pragma unroll
    for (int off = 1; off < 256; off <<= 1) {
        int x = (t >= off) ? sh[t - off] : 0;
        __syncthreads();
        sh[t] += x;
        __syncthreads();
    }
    int excl = (t == 0) ? 0 : sh[t - 1];
    #pragma unroll
    for (int i = 0; i < 4; ++i) {
        int idx = base + t * 4 + i;
        if (idx < N) ofs[idx] = excl;
        excl += v[i];
    }
    if (t == 255) bsum[blockIdx.x] = sh[255];
}

__global__ __launch_bounds__(256)
void scan_top(int* __restrict__ bsum, int nb) {
    __shared__ int sh[256];
    const int t = threadIdx.x;
    sh[t] = (t < nb) ? bsum[t] : 0;
    __syncthreads();
    #pragma unroll
    for (int off = 1; off < 256; off <<= 1) {
        int x = (t >= off) ? sh[t - off] : 0;
        __syncthreads();
        sh[t] += x;
        __syncthreads();
    }
    int excl = (t == 0) ? 0 : sh[t - 1];
    if (t < nb) bsum[t] = excl;
}

__global__ void add_offsets(int* __restrict__ ofs, const int* __restrict__ bsum,
                            int* __restrict__ cursor, int N, int E) {
    int i = blockIdx.x * blockDim.x + threadIdx.x;
    if (i < N) {
        int v = ofs[i] + bsum[i >> 10];
        ofs[i] = v;
        cursor[i] = v;
    }
    if (i == 0) ofs[N] = E;
}

// CSR fill: packed (src, w_layer) metadata per layer, in dst-CSR order.
__global__ void fill_csr(const int* __restrict__ src, const int* __restrict__ dst,
                         int* __restrict__ cursor, const float* __restrict__ w, int E,
                         float2* __restrict__ sw0, float2* __restrict__ sw1,
                         float2* __restrict__ sw2) {
    int e = blockIdx.x * blockDim.x + threadIdx.x;
    if (e < E) {
        int pos = atomicAdd(&cursor[dst[e]], 1);
        float sx = __int_as_float(src[e]);
        sw0[pos] = make_float2(sx, w[e]);
        sw1[pos] = make_float2(sx, w[E + e]);
        sw2[pos] = make_float2(sx, w[2 * (size_t)E + e]);
    }
}

// y[N][PC](bf16) = (h[N][128](f32) * invo[row]) @ W[128][dact]  (cols>=dact -> 0)
template<int PC>
__global__ __launch_bounds__(256)
void gemm_kernel(const float* __restrict__ h, const float* __restrict__ invo,
                 const float* __restrict__ W, int dact,
                 unsigned short* __restrict__ y, int N) {
    constexpr int NC   = PC / 4;
    constexpr int NR   = 256 / NC;
    constexpr int ROWS = NR * 4;
    __shared__ float Ws[128 * PC];
    __shared__ float hs[ROWS * 128];

    for (int idx = threadIdx.x; idx < 128 * PC; idx += 256) {
        int k = idx / PC, j = idx % PC;
        Ws[idx] = (j < dact) ? W[k * dact + j] : 0.0f;
    }

    const int row0 = blockIdx.x * ROWS;
    for (int i = threadIdx.x; i < ROWS * 32; i += 256) {
        int r = i >> 5, c4 = i & 31;
        int row = row0 + r;
        float4 v = make_float4(0.f, 0.f, 0.f, 0.f);
        float s = 0.f;
        if (row < N) {
            v = *(const float4*)&h[(size_t)row * 128 + c4 * 4];
            s = invo[row];
        }
        v.x *= s; v.y *= s; v.z *= s; v.w *= s;
        *(float4*)&hs[r * 128 + c4 * 4] = v;
    }
    __syncthreads();

    const int tc = threadIdx.x % NC;
    const int tr = threadIdx.x / NC;
    const int jb = tc * 4;
    const int rb = tr * 4;

    float acc[4][4];
    #pragma unroll
    for (int r = 0; r < 4; ++r)
        #pragma unroll
        for (int c = 0; c < 4; ++c) acc[r][c] = 0.f;

    #pragma unroll 2
    for (int k = 0; k < 128; k += 4) {
        float4 wv0 = *(const float4*)&Ws[(k + 0) * PC + jb];
        float4 wv1 = *(const float4*)&Ws[(k + 1) * PC + jb];
        float4 wv2 = *(const float4*)&Ws[(k + 2) * PC + jb];
        float4 wv3 = *(const float4*)&Ws[(k + 3) * PC + jb];
        #pragma unroll
        for (int r = 0; r < 4; ++r) {
            float4 hv = *(const float4*)&hs[(rb + r) * 128 + k];
            acc[r][0] = fmaf(hv.x, wv0.x, acc[r][0]);
            acc[r][0] = fmaf(hv.y, wv1.x, acc[r][0]);
            acc[r][0] = fmaf(hv.z, wv2.x, acc[r][0]);
            acc[r][0] = fmaf(hv.w, wv3.x, acc[r][0]);
            acc[r][1] = fmaf(hv.x, wv0.y, acc[r][1]);
            acc[r][1] = fmaf(hv.y, wv1.y, acc[r][1]);
            acc[r][1] = fmaf(hv.z, wv2.y, acc[r][1]);
            acc[r][1] = fmaf(hv.w, wv3.y, acc[r][1]);
            acc[r][2] = fmaf(hv.x, wv0.z, acc[r][2]);
            acc[r][2] = fmaf(hv.y, wv1.z, acc[r][2]);
            acc[r][2] = fmaf(hv.z, wv2.z, acc[r][2]);
            acc[r][2] = fmaf(hv.w, wv3.z, acc[r][2]);
            acc[r][3] = fmaf(hv.x, wv0.w, acc[r][3]);
            acc[r][3] = fmaf(hv.y, wv1.w, acc[r][3]);
            acc[r][3] = fmaf(hv.z, wv2.w, acc[r][3]);
            acc[r][3] = fmaf(hv.w, wv3.w, acc[r][3]);
        }
    }

    #pragma unroll
    for (int r = 0; r < 4; ++r) {
        int row = row0 + rb + r;
        if (row < N) {
            ushort4 o;
            o.x = f2bf(acc[r][0]); o.y = f2bf(acc[r][1]);
            o.z = f2bf(acc[r][2]); o.w = f2bf(acc[r][3]);
            *(ushort4*)&y[(size_t)row * PC + jb] = o;
        }
    }
}

// Pull-mode aggregation + fused finalize, y in bf16.
// D = feature pitch of y (128 or 64). Each thread handles 4 features.
template<int D, bool RELU, bool FINAL>
__global__ __launch_bounds__(256)
void gather_kernel(const unsigned short* __restrict__ yb, const int* __restrict__ row_ofs,
                   const float2* __restrict__ sw, const float* __restrict__ invi,
                   const float* __restrict__ b, float* __restrict__ out, int N) {
    constexpr int TPN = D / 4;          // threads per node
    constexpr int NPB = 256 / TPN;      // nodes per block
    const int n    = blockIdx.x * NPB + threadIdx.x / TPN;
    const int lane = threadIdx.x % TPN; // ushort4 index within the row
    if (n >= N) return;

    const ushort4* yv = (const ushort4*)yb;
    const int p1 = row_ofs[n + 1];
    int p = row_ofs[n];

    float a0 = 0.f, a1 = 0.f, a2 = 0.f, a3 = 0.f;

    for (; p + 2 <= p1; p += 2) {
        float2 m0 = sw[p];
        float2 m1 = sw[p + 1];
        int s0 = __float_as_int(m0.x);
        int s1 = __float_as_int(m1.x);
        ushort4 v0 = yv[(size_t)s0 * TPN + lane];
        ushort4 v1 = yv[(size_t)s1 * TPN + lane];
        a0 = fmaf(bf2f(v0.x), m0.y, a0);
        a1 = fmaf(bf2f(v0.y), m0.y, a1);
        a2 = fmaf(bf2f(v0.z), m0.y, a2);
        a3 = fmaf(bf2f(v0.w), m0.y, a3);
        a0 = fmaf(bf2f(v1.x), m1.y, a0);
        a1 = fmaf(bf2f(v1.y), m1.y, a1);
        a2 = fmaf(bf2f(v1.z), m1.y, a2);
        a3 = fmaf(bf2f(v1.w), m1.y, a3);
    }
    if (p < p1) {
        float2 m0 = sw[p];
        int s0 = __float_as_int(m0.x);
        ushort4 v0 = yv[(size_t)s0 * TPN + lane];
        a0 = fmaf(bf2f(v0.x), m0.y, a0);
        a1 = fmaf(bf2f(v0.y), m0.y, a1);
        a2 = fmaf(bf2f(v0.z), m0.y, a2);
        a3 = fmaf(bf2f(v0.w), m0.y, a3);
    }

    const float inv = invi[n];
    if (FINAL) {
        const int c = lane * 4;
        float acc[4] = {a0, a1, a2, a3};
        #pragma unroll
        for (int j = 0; j < 4; ++j) {
            if (c + j < 47) out[(size_t)n * 47 + c + j] = fmaf(acc[j], inv, b[c + j]);
        }
    } else {
        float4 bb = *(const float4*)&b[lane * 4];
        float4 v;
        v.x = fmaf(a0, inv, bb.x);
        v.y = fmaf(a1, inv, bb.y);
        v.z = fmaf(a2, inv, bb.z);
        v.w = fmaf(a3, inv, bb.w);
        if (RELU) {
            v.x = fmaxf(v.x, 0.f); v.y = fmaxf(v.y, 0.f);
            v.z = fmaxf(v.z, 0.f); v.w = fmaxf(v.w, 0.f);
        }
        *(float4*)&out[(size_t)n * D + lane * 4] = v;
    }
}

extern "C" void kernel_launch(void* const* d_in, const int* in_sizes, int n_in,
                              void* d_out, int out_size, void* d_ws, size_t ws_size,
                              hipStream_t stream) {
    const float* x   = (const float*)d_in[0];
    const int*   src = (const int*)d_in[1];
    const int*   dst = (const int*)d_in[2];
    const float* w   = (const float*)d_in[3];
    const float* W0  = (const float*)d_in[4];
    const float* b0  = (const float*)d_in[5];
    const float* W1  = (const float*)d_in[6];
    const float* b1  = (const float*)d_in[7];
    const float* W2  = (const float*)d_in[8];
    const float* b2  = (const float*)d_in[9];

    const int N = in_sizes[0] / 128;
    const int E = in_sizes[1];

    char* p = (char*)d_ws;
    unsigned short* y = (unsigned short*)p; p += (size_t)N * 128 * sizeof(unsigned short);
    float* hb      = (float*)p;  p += (size_t)N * 128 * sizeof(float);
    float2* sw0    = (float2*)p; p += (size_t)E * sizeof(float2);
    float2* sw1    = (float2*)p; p += (size_t)E * sizeof(float2);
    float2* sw2    = (float2*)p; p += (size_t)E * sizeof(float2);
    int*   row_ofs = (int*)p;    p += (size_t)(N + 1) * sizeof(int);
    int*   cursor  = (int*)p;    p += (size_t)N * sizeof(int);
    int*   dego    = (int*)p;    p += (size_t)N * sizeof(int);
    int*   degi    = (int*)p;    p += (size_t)N * sizeof(int);
    float* invo    = (float*)p;  p += (size_t)N * sizeof(float);
    float* invi    = (float*)p;  p += (size_t)N * sizeof(float);
    int*   bsum    = (int*)p;    p += 256 * sizeof(int);

    // ---- degrees, norms, CSR build (reused by all 3 layers) ----
    hipMemsetAsync(dego, 0, 2 * (size_t)N * sizeof(int), stream);
    deg_kernel<<<(E + 255) / 256, 256, 0, stream>>>(src, dst, dego, degi, E);
    invsqrt_kernel<<<(N + 255) / 256, 256, 0, stream>>>(dego, degi, invo, invi, N);

    const int nb = (N + 1023) / 1024;
    scan_block<<<nb, 256, 0, stream>>>(degi, row_ofs, bsum, N);
    scan_top<<<1, 256, 0, stream>>>(bsum, nb);
    add_offsets<<<(N + 255) / 256, 256, 0, stream>>>(row_ofs, bsum, cursor, N, E);
    fill_csr<<<(E + 255) / 256, 256, 0, stream>>>(src, dst, cursor, w, E, sw0, sw1, sw2);

    // ---- layer 0: x -> hb ----
    gemm_kernel<128><<<(N + 31) / 32, 256, 0, stream>>>(x, invo, W0, 128, y, N);
    gather_kernel<128, true, false><<<(N + 7) / 8, 256, 0, stream>>>(
        y, row_ofs, sw0, invi, b0, hb, N);

    // ---- layer 1: hb -> hb ----
    gemm_kernel<128><<<(N + 31) / 32, 256, 0, stream>>>(hb, invo, W1, 128, y, N);
    gather_kernel<128, true, false><<<(N + 7) / 8, 256, 0, stream>>>(
        y, row_ofs, sw1, invi, b1, hb, N);

    // ---- layer 2: hb -> d_out (47 cols, y padded to 64) ----
    gemm_kernel<64><<<(N + 63) / 64, 256, 0, stream>>>(hb, invo, W2, 47, y, N);
    gather_kernel<64, false, true><<<(N + 15) / 16, 256, 0, stream>>>(
        y, row_ofs, sw2, invi, b2, (float*)d_out, N);
}

// Round 4
// 357.879 us; speedup vs baseline: 3.5386x; 1.4377x over previous
//
#include <hip/hip_runtime.h>

// ---------------------------------------------------------------------------
// 3-layer GCN (DGL GraphConv, norm='both') on N=100k nodes, E=800k edges.
// Round 4: GEMM switched to bf16 MFMA (v_mfma_f32_16x16x32_bf16), f32 accum.
// A and B fragments use the SAME (group,reg)->k mapping, so the HW's internal
// k-labeling cancels; only the C/D layout (col=lane&15, row=(lane>>4)*4+reg)
// matters. W pre-packed into fragment order in LDS; h tile at pitch 136 bf16.
// Per layer: y = bf16((h*invo) @ W) ; h' = relu(CSR-gather(y)*invi + b)
// ---------------------------------------------------------------------------

typedef short s16x8 __attribute__((ext_vector_type(8)));
typedef float f32x4 __attribute__((ext_vector_type(4)));

__device__ __forceinline__ unsigned short f2bf(float f) {
    unsigned int u = __float_as_uint(f);
    u += 0x7FFFu + ((u >> 16) & 1u);   // round-to-nearest-even
    return (unsigned short)(u >> 16);
}
__device__ __forceinline__ float bf2f(unsigned short v) {
    return __uint_as_float((unsigned int)v << 16);
}

__global__ void deg_kernel(const int* __restrict__ src, const int* __restrict__ dst,
                           int* __restrict__ dego, int* __restrict__ degi, int E) {
    int e = blockIdx.x * blockDim.x + threadIdx.x;
    if (e < E) {
        atomicAdd(&dego[src[e]], 1);
        atomicAdd(&degi[dst[e]], 1);
    }
}

__global__ void invsqrt_kernel(const int* __restrict__ dego, const int* __restrict__ degi,
                               float* __restrict__ invo, float* __restrict__ invi, int N) {
    int i = blockIdx.x * blockDim.x + threadIdx.x;
    if (i < N) {
        int a = dego[i]; if (a < 1) a = 1;
        int b = degi[i]; if (b < 1) b = 1;
        invo[i] = 1.0f / sqrtf((float)a);
        invi[i] = 1.0f / sqrtf((float)b);
    }
}

// ---- prefix sum of degi -> row_ofs (exclusive), 1024 elems per block ----
__global__ __launch_bounds__(256)
void scan_block(const int* __restrict__ deg, int* __restrict__ ofs,
                int* __restrict__ bsum, int N) {
    __shared__ int sh[256];
    const int base = blockIdx.x * 1024;
    const int t = threadIdx.x;
    int v[4]; int s = 0;
    #pragma unroll
    for (int i = 0; i < 4; ++i) {
        int idx = base + t * 4 + i;
        v[i] = (idx < N) ? deg[idx] : 0;
        s += v[i];
    }
    sh[t] = s;
    __syncthreads();
    #pragma unroll
    for (int off = 1; off < 256; off <<= 1) {
        int x = (t >= off) ? sh[t - off] : 0;
        __syncthreads();
        sh[t] += x;
        __syncthreads();
    }
    int excl = (t == 0) ? 0 : sh[t - 1];
    #pragma unroll
    for (int i = 0; i < 4; ++i) {
        int idx = base + t * 4 + i;
        if (idx < N) ofs[idx] = excl;
        excl += v[i];
    }
    if (t == 255) bsum[blockIdx.x] = sh[255];
}

__global__ __launch_bounds__(256)
void scan_top(int* __restrict__ bsum, int nb) {
    __shared__ int sh[256];
    const int t = threadIdx.x;
    sh[t] = (t < nb) ? bsum[t] : 0;
    __syncthreads();
    #pragma unroll
    for (int off = 1; off < 256; off <<= 1) {
        int x = (t >= off) ? sh[t - off] : 0;
        __syncthreads();
        sh[t] += x;
        __syncthreads();
    }
    int excl = (t == 0) ? 0 : sh[t - 1];
    if (t < nb) bsum[t] = excl;
}

__global__ void add_offsets(int* __restrict__ ofs, const int* __restrict__ bsum,
                            int* __restrict__ cursor, int N, int E) {
    int i = blockIdx.x * blockDim.x + threadIdx.x;
    if (i < N) {
        int v = ofs[i] + bsum[i >> 10];
        ofs[i] = v;
        cursor[i] = v;
    }
    if (i == 0) ofs[N] = E;
}

// CSR fill: packed (src, w_layer) metadata per layer, in dst-CSR order.
__global__ void fill_csr(const int* __restrict__ src, const int* __restrict__ dst,
                         int* __restrict__ cursor, const float* __restrict__ w, int E,
                         float2* __restrict__ sw0, float2* __restrict__ sw1,
                         float2* __restrict__ sw2) {
    int e = blockIdx.x * blockDim.x + threadIdx.x;
    if (e < E) {
        int pos = atomicAdd(&cursor[dst[e]], 1);
        float sx = __int_as_float(src[e]);
        sw0[pos] = make_float2(sx, w[e]);
        sw1[pos] = make_float2(sx, w[E + e]);
        sw2[pos] = make_float2(sx, w[2 * (size_t)E + e]);
    }
}

// ---------------------------------------------------------------------------
// MFMA GEMM: y[N][PC](bf16) = bf16( (h[N][128](f32) * invo[row]) @ W[128][dact] )
// Block: 256 threads = 4 waves; 64 rows per block; each wave 16 rows x PC cols.
// K = 128 = 4 steps of 32. Fragment k-mapping: k = kk*32 + (lane>>4)*8 + j,
// used identically for A and B (cancels HW-internal ordering).
// ---------------------------------------------------------------------------
template<int PC>
__global__ __launch_bounds__(256)
void gemm_mfma(const float* __restrict__ h, const float* __restrict__ invo,
               const float* __restrict__ W, int dact,
               unsigned short* __restrict__ y, int N) {
    constexpr int CT = PC / 16;      // 16-col tiles
    constexpr int HP = 136;          // h-tile pitch in bf16 elements
    __shared__ unsigned short Wf[4 * CT * 64 * 8];   // [kk][ct][lane][j]
    __shared__ unsigned short hsb[64 * HP];

    // ---- stage W into fragment order (bf16) ----
    if (dact == PC) {   // fast path: rows are 16B-aligned, float4 loads
        for (int idx = threadIdx.x; idx < 128 * (PC / 4); idx += 256) {
            int k   = idx / (PC / 4);
            int col = (idx % (PC / 4)) * 4;
            float4 wv = *(const float4*)&W[(size_t)k * PC + col];
            int kk = k >> 5, kr = k & 31;
            int lane = ((kr >> 3) << 4) | (col & 15);
            int ct = col >> 4, j = kr & 7;
            unsigned short* d = &Wf[(((kk * CT) + ct) * 64 + lane) * 8 + j];
            d[0]  = f2bf(wv.x);
            d[8]  = f2bf(wv.y);
            d[16] = f2bf(wv.z);
            d[24] = f2bf(wv.w);
        }
    } else {            // dact < PC: scalar loads, zero-pad cols >= dact
        for (int idx = threadIdx.x; idx < 128 * PC; idx += 256) {
            int k = idx / PC, col = idx % PC;
            float wv = (col < dact) ? W[(size_t)k * dact + col] : 0.0f;
            int kk = k >> 5, kr = k & 31;
            int lane = ((kr >> 3) << 4) | (col & 15);
            int ct = col >> 4, j = kr & 7;
            Wf[(((kk * CT) + ct) * 64 + lane) * 8 + j] = f2bf(wv);
        }
    }

    // ---- stage h tile (scaled by invo, converted to bf16), pitch HP ----
    const int row0 = blockIdx.x * 64;
    for (int i = threadIdx.x; i < 64 * 32; i += 256) {
        int r = i >> 5, c4 = i & 31;
        int row = row0 + r;
        float4 v = make_float4(0.f, 0.f, 0.f, 0.f);
        float s = 0.f;
        if (row < N) {
            v = *(const float4*)&h[(size_t)row * 128 + c4 * 4];
            s = invo[row];
        }
        ushort4 o;
        o.x = f2bf(v.x * s); o.y = f2bf(v.y * s);
        o.z = f2bf(v.z * s); o.w = f2bf(v.w * s);
        *(ushort4*)&hsb[r * HP + c4 * 4] = o;
    }
    __syncthreads();

    // ---- MFMA compute ----
    const int lane = threadIdx.x & 63;
    const int wid  = threadIdx.x >> 6;
    const int wr0  = wid * 16;               // wave's row offset in tile
    const int arow = wr0 + (lane & 15);
    const int kgrp = lane >> 4;              // 0..3

    f32x4 acc[CT];
    #pragma unroll
    for (int ct = 0; ct < CT; ++ct) acc[ct] = {0.f, 0.f, 0.f, 0.f};

    #pragma unroll
    for (int kk = 0; kk < 4; ++kk) {
        s16x8 af = *(const s16x8*)&hsb[arow * HP + kk * 32 + kgrp * 8];
        #pragma unroll
        for (int ct = 0; ct < CT; ++ct) {
            s16x8 bf = *(const s16x8*)&Wf[((kk * CT + ct) * 64 + lane) * 8];
            acc[ct] = __builtin_amdgcn_mfma_f32_16x16x32_bf16(af, bf, acc[ct], 0, 0, 0);
        }
    }

    // ---- store C (bf16): col = ct*16 + (lane&15), row = wr0 + (lane>>4)*4 + i
    const int c = lane & 15;
    #pragma unroll
    for (int ct = 0; ct < CT; ++ct) {
        #pragma unroll
        for (int i = 0; i < 4; ++i) {
            int row = row0 + wr0 + kgrp * 4 + i;
            if (row < N) y[(size_t)row * PC + ct * 16 + c] = f2bf(acc[ct][i]);
        }
    }
}

// Pull-mode aggregation + fused finalize, y in bf16.
// D = feature pitch of y (128 or 64). Each thread handles 4 features.
template<int D, bool RELU, bool FINAL>
__global__ __launch_bounds__(256)
void gather_kernel(const unsigned short* __restrict__ yb, const int* __restrict__ row_ofs,
                   const float2* __restrict__ sw, const float* __restrict__ invi,
                   const float* __restrict__ b, float* __restrict__ out, int N) {
    constexpr int TPN = D / 4;          // threads per node
    constexpr int NPB = 256 / TPN;      // nodes per block
    const int n    = blockIdx.x * NPB + threadIdx.x / TPN;
    const int lane = threadIdx.x % TPN; // ushort4 index within the row
    if (n >= N) return;

    const ushort4* yv = (const ushort4*)yb;
    const int p1 = row_ofs[n + 1];
    int p = row_ofs[n];

    float a0 = 0.f, a1 = 0.f, a2 = 0.f, a3 = 0.f;

    for (; p + 2 <= p1; p += 2) {
        float2 m0 = sw[p];
        float2 m1 = sw[p + 1];
        int s0 = __float_as_int(m0.x);
        int s1 = __float_as_int(m1.x);
        ushort4 v0 = yv[(size_t)s0 * TPN + lane];
        ushort4 v1 = yv[(size_t)s1 * TPN + lane];
        a0 = fmaf(bf2f(v0.x), m0.y, a0);
        a1 = fmaf(bf2f(v0.y), m0.y, a1);
        a2 = fmaf(bf2f(v0.z), m0.y, a2);
        a3 = fmaf(bf2f(v0.w), m0.y, a3);
        a0 = fmaf(bf2f(v1.x), m1.y, a0);
        a1 = fmaf(bf2f(v1.y), m1.y, a1);
        a2 = fmaf(bf2f(v1.z), m1.y, a2);
        a3 = fmaf(bf2f(v1.w), m1.y, a3);
    }
    if (p < p1) {
        float2 m0 = sw[p];
        int s0 = __float_as_int(m0.x);
        ushort4 v0 = yv[(size_t)s0 * TPN + lane];
        a0 = fmaf(bf2f(v0.x), m0.y, a0);
        a1 = fmaf(bf2f(v0.y), m0.y, a1);
        a2 = fmaf(bf2f(v0.z), m0.y, a2);
        a3 = fmaf(bf2f(v0.w), m0.y, a3);
    }

    const float inv = invi[n];
    if (FINAL) {
        const int c = lane * 4;
        float acc[4] = {a0, a1, a2, a3};
        #pragma unroll
        for (int j = 0; j < 4; ++j) {
            if (c + j < 47) out[(size_t)n * 47 + c + j] = fmaf(acc[j], inv, b[c + j]);
        }
    } else {
        float4 bb = *(const float4*)&b[lane * 4];
        float4 v;
        v.x = fmaf(a0, inv, bb.x);
        v.y = fmaf(a1, inv, bb.y);
        v.z = fmaf(a2, inv, bb.z);
        v.w = fmaf(a3, inv, bb.w);
        if (RELU) {
            v.x = fmaxf(v.x, 0.f); v.y = fmaxf(v.y, 0.f);
            v.z = fmaxf(v.z, 0.f); v.w = fmaxf(v.w, 0.f);
        }
        *(float4*)&out[(size_t)n * D + lane * 4] = v;
    }
}

extern "C" void kernel_launch(void* const* d_in, const int* in_sizes, int n_in,
                              void* d_out, int out_size, void* d_ws, size_t ws_size,
                              hipStream_t stream) {
    const float* x   = (const float*)d_in[0];
    const int*   src = (const int*)d_in[1];
    const int*   dst = (const int*)d_in[2];
    const float* w   = (const float*)d_in[3];
    const float* W0  = (const float*)d_in[4];
    const float* b0  = (const float*)d_in[5];
    const float* W1  = (const float*)d_in[6];
    const float* b1  = (const float*)d_in[7];
    const float* W2  = (const float*)d_in[8];
    const float* b2  = (const float*)d_in[9];

    const int N = in_sizes[0] / 128;
    const int E = in_sizes[1];

    char* p = (char*)d_ws;
    unsigned short* y = (unsigned short*)p; p += (size_t)N * 128 * sizeof(unsigned short);
    float* hb      = (float*)p;  p += (size_t)N * 128 * sizeof(float);
    float2* sw0    = (float2*)p; p += (size_t)E * sizeof(float2);
    float2* sw1    = (float2*)p; p += (size_t)E * sizeof(float2);
    float2* sw2    = (float2*)p; p += (size_t)E * sizeof(float2);
    int*   row_ofs = (int*)p;    p += (size_t)(N + 1) * sizeof(int);
    int*   cursor  = (int*)p;    p += (size_t)N * sizeof(int);
    int*   dego    = (int*)p;    p += (size_t)N * sizeof(int);
    int*   degi    = (int*)p;    p += (size_t)N * sizeof(int);
    float* invo    = (float*)p;  p += (size_t)N * sizeof(float);
    float* invi    = (float*)p;  p += (size_t)N * sizeof(float);
    int*   bsum    = (int*)p;    p += 256 * sizeof(int);

    // ---- degrees, norms, CSR build (reused by all 3 layers) ----
    hipMemsetAsync(dego, 0, 2 * (size_t)N * sizeof(int), stream);
    deg_kernel<<<(E + 255) / 256, 256, 0, stream>>>(src, dst, dego, degi, E);
    invsqrt_kernel<<<(N + 255) / 256, 256, 0, stream>>>(dego, degi, invo, invi, N);

    const int nb = (N + 1023) / 1024;
    scan_block<<<nb, 256, 0, stream>>>(degi, row_ofs, bsum, N);
    scan_top<<<1, 256, 0, stream>>>(bsum, nb);
    add_offsets<<<(N + 255) / 256, 256, 0, stream>>>(row_ofs, bsum, cursor, N, E);
    fill_csr<<<(E + 255) / 256, 256, 0, stream>>>(src, dst, cursor, w, E, sw0, sw1, sw2);

    const int gemm_blocks = (N + 63) / 64;

    // ---- layer 0: x -> hb ----
    gemm_mfma<128><<<gemm_blocks, 256, 0, stream>>>(x, invo, W0, 128, y, N);
    gather_kernel<128, true, false><<<(N + 7) / 8, 256, 0, stream>>>(
        y, row_ofs, sw0, invi, b0, hb, N);

    // ---- layer 1: hb -> hb ----
    gemm_mfma<128><<<gemm_blocks, 256, 0, stream>>>(hb, invo, W1, 128, y, N);
    gather_kernel<128, true, false><<<(N + 7) / 8, 256, 0, stream>>>(
        y, row_ofs, sw1, invi, b1, hb, N);

    // ---- layer 2: hb -> d_out (47 cols, y padded to 64) ----
    gemm_mfma<64><<<gemm_blocks, 256, 0, stream>>>(hb, invo, W2, 47, y, N);
    gather_kernel<64, false, true><<<(N + 15) / 16, 256, 0, stream>>>(
        y, row_ofs, sw2, invi, b2, (float*)d_out, N);
}